// Round 4
// baseline (2854.246 us; speedup 1.0000x reference)
//
#include <hip/hip_runtime.h>
#include <hip/hip_bf16.h>

#define NL 6
#define DT 6144
#define DM 768
#define TOK 128

#define TD 256            // decode d-tile width
#define NTD 3             // d-tiles
#define FC 384            // decode f-chunk
#define NFC 16            // f-chunks
#define NSTEP (FC / 32)   // 12 k-steps per block

#define DREP 8            // MEASUREMENT: repeat decode sweep 8x, scale by 1/8
#define EREP 24           // MEASUREMENT: repeat encode body 24x (idempotent)

using bf16x8 = __attribute__((ext_vector_type(8))) short;
using f32x4  = __attribute__((ext_vector_type(4))) float;

typedef unsigned int u32;
typedef __attribute__((address_space(1))) const u32 gu32;
typedef __attribute__((address_space(3))) u32 lu32;

// async global->LDS, 16B per lane; LDS dest = wave-uniform base + lane*16
__device__ __forceinline__ void stage16(const float* g, float* l) {
  __builtin_amdgcn_global_load_lds((gu32*)g, (lu32*)l, 16, 0, 0);
}

// round-to-nearest-even f32 -> bf16 (branchless; inputs are finite)
__device__ __forceinline__ short f2bf(float f) {
  union { float f; unsigned u; } c; c.f = f;
  unsigned u = c.u;
  u += 0x7fffu + ((u >> 16) & 1u);
  return (short)(u >> 16);
}

__device__ __forceinline__ bf16x8 cvt8(float4 v0, float4 v1) {
  bf16x8 r;
  r[0] = f2bf(v0.x); r[1] = f2bf(v0.y); r[2] = f2bf(v0.z); r[3] = f2bf(v0.w);
  r[4] = f2bf(v1.x); r[5] = f2bf(v1.y); r[6] = f2bf(v1.z); r[7] = f2bf(v1.w);
  return r;
}

// out[j][n][d] = b_dec[j][d]
__global__ void init_k(const float* __restrict__ b_dec, float* __restrict__ out) {
  int idx = blockIdx.x * 256 + threadIdx.x;
  if (idx < NL * TOK * DM) {
    out[idx] = b_dec[(idx / (TOK * DM)) * DM + (idx % DM)];
  }
}

// acts[l][n][f] = relu(x[l] @ W_enc[l]^T + b_enc[l]), bf16 output
// MEASUREMENT ROUND: body repeated EREP times (idempotent) to expose counters.
__global__ __launch_bounds__(256) void encode_k(
    const float* __restrict__ x, const float* __restrict__ W_enc,
    const float* __restrict__ b_enc, ushort* __restrict__ acts)
{
  const int bid = blockIdx.x;
  const int l   = bid / 96;
  const int r   = bid % 96;
  const int f0  = (r >> 1) * 128;
  const int mt  = r & 1;
  const int wave = threadIdx.x >> 6;
  const int lane = threadIdx.x & 63;
  const int lo = lane & 15, hi = lane >> 4;
  const int fw = f0 + wave * 32;
  const int m0 = mt * 64;

  const float* xl = x + (size_t)l * TOK * DM;
  const float* We = W_enc + (size_t)l * DT * DM;

  #pragma unroll 1
  for (int rep = 0; rep < EREP; ++rep) {
    f32x4 acc[4][2];
    #pragma unroll
    for (int mi = 0; mi < 4; ++mi)
      #pragma unroll
      for (int ni = 0; ni < 2; ++ni)
        acc[mi][ni] = f32x4{0.f, 0.f, 0.f, 0.f};

    #pragma unroll 2
    for (int d0 = 0; d0 < DM; d0 += 32) {
      const int ka = d0 + hi * 8;
      bf16x8 a[4], b[2];
      #pragma unroll
      for (int mi = 0; mi < 4; ++mi) {
        const float* p = xl + (size_t)(m0 + mi * 16 + lo) * DM + ka;
        a[mi] = cvt8(*(const float4*)p, *(const float4*)(p + 4));
      }
      #pragma unroll
      for (int ni = 0; ni < 2; ++ni) {
        const float* p = We + (size_t)(fw + ni * 16 + lo) * DM + ka;
        b[ni] = cvt8(*(const float4*)p, *(const float4*)(p + 4));
      }
      #pragma unroll
      for (int mi = 0; mi < 4; ++mi)
        #pragma unroll
        for (int ni = 0; ni < 2; ++ni)
          acc[mi][ni] = __builtin_amdgcn_mfma_f32_16x16x32_bf16(a[mi], b[ni], acc[mi][ni], 0, 0, 0);
    }

    #pragma unroll
    for (int ni = 0; ni < 2; ++ni) {
      const int f = fw + ni * 16 + lo;
      const float bias = b_enc[l * DT + f];
      #pragma unroll
      for (int mi = 0; mi < 4; ++mi) {
        #pragma unroll
        for (int rr = 0; rr < 4; ++rr) {
          const int n = m0 + mi * 16 + hi * 4 + rr;
          float v = acc[mi][ni][rr] + bias;
          v = v > 0.f ? v : 0.f;
          acts[((size_t)l * TOK + n) * DT + f] = (ushort)f2bf(v);
        }
      }
    }
  }
}

// pair enumeration (i <= j), 21 valid decoder blocks
__device__ const int PI_[21] = {0,0,0,0,0,0, 1,1,1,1,1, 2,2,2,2, 3,3,3, 4,4, 5};
__device__ const int PJ_[21] = {0,1,2,3,4,5, 1,2,3,4,5, 2,3,4,5, 3,4,5, 4,5, 5};

// out[j] += acts[i] @ W_dec[i][j], one (i,j) pair per block (uniform work).
// MEASUREMENT ROUND: k-sweep repeated DREP times into the same acc,
// scaled by 1/DREP (exact pow2) in the epilogue. Structure otherwise = round 3.
__global__ __launch_bounds__(256, 2) void decode_k(
    const ushort* __restrict__ acts, const float* __restrict__ W_dec,
    float* __restrict__ out)
{
  __shared__ float lw[2][32][TD];   // 64 KB

  const int bid = blockIdx.x;
  const int p  = bid / (NTD * NFC);
  const int rm = bid % (NTD * NFC);
  const int c  = rm / NTD;
  const int t  = rm % NTD;
  const int i = PI_[p], j = PJ_[p];
  const int w = threadIdx.x >> 6;
  const int lane = threadIdx.x & 63;
  const int lo = lane & 15, hi = lane >> 4;
  const int fb = c * FC;

  const float*  Wb = W_dec + ((size_t)(i * NL + j) * DT + fb) * DM + t * TD;
  const ushort* Ab = acts + (size_t)i * TOK * DT + fb;

  f32x4 acc[8][4];
  #pragma unroll
  for (int mi = 0; mi < 8; ++mi)
    #pragma unroll
    for (int ni = 0; ni < 4; ++ni)
      acc[mi][ni] = f32x4{0.f, 0.f, 0.f, 0.f};

  #pragma unroll 1
  for (int rep = 0; rep < DREP; ++rep) {
    // stage step 0: one full 1KB row per wave-instruction (perfect coalescing)
    #pragma unroll
    for (int q = 0; q < 8; ++q) {
      const int row = w * 8 + q;
      stage16(Wb + (size_t)row * DM + lane * 4, &lw[0][row][0]);
    }
    __syncthreads();

    int cur = 0;
    #pragma unroll 1
    for (int s = 0; s < NSTEP; ++s) {
      if (s + 1 < NSTEP) {
        const float* Ws = Wb + (size_t)(s + 1) * 32 * DM;
        #pragma unroll
        for (int q = 0; q < 8; ++q) {
          const int row = w * 8 + q;
          stage16(Ws + (size_t)row * DM + lane * 4, &lw[cur ^ 1][row][0]);
        }
      }

      bf16x8 a[8];
      #pragma unroll
      for (int mi = 0; mi < 8; ++mi)
        a[mi] = *(const bf16x8*)(Ab + (size_t)(mi * 16 + lo) * DT + s * 32 + hi * 8);

      bf16x8 b[4];
      #pragma unroll
      for (int ni = 0; ni < 4; ++ni) {
        const int col = w * 64 + ni * 16 + lo;
        #pragma unroll
        for (int e = 0; e < 8; ++e)
          b[ni][e] = f2bf(lw[cur][hi * 8 + e][col]);
      }

      #pragma unroll
      for (int mi = 0; mi < 8; ++mi)
        #pragma unroll
        for (int ni = 0; ni < 4; ++ni)
          acc[mi][ni] = __builtin_amdgcn_mfma_f32_16x16x32_bf16(a[mi], b[ni], acc[mi][ni], 0, 0, 0);

      __syncthreads();
      cur ^= 1;
    }
  }

  const float scale = 1.0f / DREP;   // exact (pow2)
  float* oj = out + (size_t)j * TOK * DM;
  #pragma unroll
  for (int ni = 0; ni < 4; ++ni) {
    const int d = t * TD + w * 64 + ni * 16 + lo;
    #pragma unroll
    for (int mi = 0; mi < 8; ++mi)
      #pragma unroll
      for (int rr = 0; rr < 4; ++rr)
        atomicAdd(oj + (size_t)(mi * 16 + hi * 4 + rr) * DM + d, acc[mi][ni][rr] * scale);
  }
}

extern "C" void kernel_launch(void* const* d_in, const int* in_sizes, int n_in,
                              void* d_out, int out_size, void* d_ws, size_t ws_size,
                              hipStream_t stream) {
  const float* x     = (const float*)d_in[0];
  const float* W_enc = (const float*)d_in[1];
  const float* b_enc = (const float*)d_in[2];
  const float* b_dec = (const float*)d_in[3];
  const float* W_dec = (const float*)d_in[4];
  float* out = (float*)d_out;
  ushort* acts = (ushort*)d_ws;   // 6*128*6144 bf16 = 9.4 MB

  init_k<<<dim3((NL * TOK * DM + 255) / 256), dim3(256), 0, stream>>>(b_dec, out);
  encode_k<<<dim3(NL * 48 * 2), dim3(256), 0, stream>>>(x, W_enc, b_enc, acts);
  decode_k<<<dim3(21 * NFC * NTD), dim3(256), 0, stream>>>(acts, W_dec, out);
}

// Round 5
// 273.144 us; speedup vs baseline: 10.4496x; 10.4496x over previous
//
#include <hip/hip_runtime.h>
#include <hip/hip_bf16.h>

#define NL 6
#define DT 6144
#define DM 768
#define TOK 128

#define TD 256            // decode d-tile width
#define NTD 3             // d-tiles
#define FC 384            // decode f-chunk
#define NFC 16            // f-chunks
#define NSTEP (FC / 32)   // 12 k-steps per decode block

using bf16x8 = __attribute__((ext_vector_type(8))) short;
using f32x4  = __attribute__((ext_vector_type(4))) float;

typedef unsigned int u32;
typedef __attribute__((address_space(1))) const u32 gu32;
typedef __attribute__((address_space(3))) u32 lu32;

// async global->LDS, 16B per lane; LDS dest = wave-uniform base + lane*16
__device__ __forceinline__ void stage16(const float* g, float* l) {
  __builtin_amdgcn_global_load_lds((gu32*)g, (lu32*)l, 16, 0, 0);
}

// round-to-nearest-even f32 -> bf16 (branchless; inputs are finite)
__device__ __forceinline__ short f2bf(float f) {
  union { float f; unsigned u; } c; c.f = f;
  unsigned u = c.u;
  u += 0x7fffu + ((u >> 16) & 1u);
  return (short)(u >> 16);
}

// out[j][n][d] = b_dec[j][d]  AND  xb = bf16(x)   (same element count)
__global__ void initcvt_k(const float* __restrict__ b_dec,
                          const float* __restrict__ x,
                          float* __restrict__ out, ushort* __restrict__ xb) {
  int idx = blockIdx.x * 256 + threadIdx.x;
  if (idx < NL * TOK * DM) {
    out[idx] = b_dec[(idx / (TOK * DM)) * DM + (idx % DM)];
    xb[idx] = (ushort)f2bf(x[idx]);
  }
}

// acts[l][n][f] = relu(x[l] @ W_enc[l]^T + b_enc[l]), bf16 output.
// Decode-style streaming: W_enc k-step tiles staged via global_load_lds into
// double-buffered LDS; A (xb, bf16, L2-hot) loaded directly as dwordx4.
// grid: 6 layers * 96 f-tiles(64) = 576 blocks; 256 thr (4 waves, 16 f each).
__global__ __launch_bounds__(256) void encode_k(
    const ushort* __restrict__ xb, const float* __restrict__ W_enc,
    const float* __restrict__ b_enc, ushort* __restrict__ acts)
{
  __shared__ float lw[2][64][32];   // 16 KB double-buffered W tile

  const int l  = blockIdx.x / 96;
  const int f0 = (blockIdx.x % 96) * 64;
  const int w    = threadIdx.x >> 6;
  const int lane = threadIdx.x & 63;
  const int lo = lane & 15, hi = lane >> 4;

  const float*  We = W_enc + ((size_t)l * DT + f0) * DM;
  const ushort* Xb = xb + (size_t)l * TOK * DM;

  const int r0 = w * 16 + (lane >> 3);   // staging row (+q*8)
  const int cc = (lane & 7) * 4;         // d-chunk offset (floats)

  f32x4 acc[8];
  #pragma unroll
  for (int mi = 0; mi < 8; ++mi) acc[mi] = f32x4{0.f, 0.f, 0.f, 0.f};

  // stage step 0
  #pragma unroll
  for (int q = 0; q < 2; ++q)
    stage16(We + (size_t)(r0 + q * 8) * DM + cc, &lw[0][w * 16 + q * 8][0]);
  __syncthreads();

  int cur = 0;
  #pragma unroll 1
  for (int s = 0; s < DM / 32; ++s) {
    // fire next-step staging before compute; end-of-step barrier drains it
    if (s + 1 < DM / 32) {
      #pragma unroll
      for (int q = 0; q < 2; ++q)
        stage16(We + (size_t)(r0 + q * 8) * DM + (s + 1) * 32 + cc,
                &lw[cur ^ 1][w * 16 + q * 8][0]);
    }

    bf16x8 b;
    #pragma unroll
    for (int e = 0; e < 8; ++e)
      b[e] = f2bf(lw[cur][w * 16 + lo][hi * 8 + e]);

    bf16x8 a[8];
    #pragma unroll
    for (int mi = 0; mi < 8; ++mi)
      a[mi] = *(const bf16x8*)(Xb + (size_t)(mi * 16 + lo) * DM + s * 32 + hi * 8);

    #pragma unroll
    for (int mi = 0; mi < 8; ++mi)
      acc[mi] = __builtin_amdgcn_mfma_f32_16x16x32_bf16(a[mi], b, acc[mi], 0, 0, 0);

    __syncthreads();
    cur ^= 1;
  }

  const int f = f0 + w * 16 + lo;
  const float bias = b_enc[l * DT + f];
  #pragma unroll
  for (int mi = 0; mi < 8; ++mi) {
    #pragma unroll
    for (int rr = 0; rr < 4; ++rr) {
      const int n = mi * 16 + hi * 4 + rr;
      float v = acc[mi][rr] + bias;
      v = v > 0.f ? v : 0.f;
      acts[((size_t)l * TOK + n) * DT + f] = (ushort)f2bf(v);
    }
  }
}

// pair enumeration (i <= j), 21 valid decoder blocks
__device__ const int PI_[21] = {0,0,0,0,0,0, 1,1,1,1,1, 2,2,2,2, 3,3,3, 4,4, 5};
__device__ const int PJ_[21] = {0,1,2,3,4,5, 1,2,3,4,5, 2,3,4,5, 3,4,5, 4,5, 5};

// out[j] += acts[i] @ W_dec[i][j], one (i,j) pair per block (uniform work).
// MEASURED (r4): ~62-66 us/sweep for the 396 MB W stream = HBM roofline. Do not touch.
__global__ __launch_bounds__(256, 2) void decode_k(
    const ushort* __restrict__ acts, const float* __restrict__ W_dec,
    float* __restrict__ out)
{
  __shared__ float lw[2][32][TD];   // 64 KB

  const int bid = blockIdx.x;
  const int p  = bid / (NTD * NFC);
  const int rm = bid % (NTD * NFC);
  const int c  = rm / NTD;
  const int t  = rm % NTD;
  const int i = PI_[p], j = PJ_[p];
  const int w = threadIdx.x >> 6;
  const int lane = threadIdx.x & 63;
  const int lo = lane & 15, hi = lane >> 4;
  const int fb = c * FC;

  const float*  Wb = W_dec + ((size_t)(i * NL + j) * DT + fb) * DM + t * TD;
  const ushort* Ab = acts + (size_t)i * TOK * DT + fb;

  f32x4 acc[8][4];
  #pragma unroll
  for (int mi = 0; mi < 8; ++mi)
    #pragma unroll
    for (int ni = 0; ni < 4; ++ni)
      acc[mi][ni] = f32x4{0.f, 0.f, 0.f, 0.f};

  #pragma unroll
  for (int q = 0; q < 8; ++q) {
    const int row = w * 8 + q;
    stage16(Wb + (size_t)row * DM + lane * 4, &lw[0][row][0]);
  }
  __syncthreads();

  int cur = 0;
  #pragma unroll 1
  for (int s = 0; s < NSTEP; ++s) {
    if (s + 1 < NSTEP) {
      const float* Ws = Wb + (size_t)(s + 1) * 32 * DM;
      #pragma unroll
      for (int q = 0; q < 8; ++q) {
        const int row = w * 8 + q;
        stage16(Ws + (size_t)row * DM + lane * 4, &lw[cur ^ 1][row][0]);
      }
    }

    bf16x8 a[8];
    #pragma unroll
    for (int mi = 0; mi < 8; ++mi)
      a[mi] = *(const bf16x8*)(Ab + (size_t)(mi * 16 + lo) * DT + s * 32 + hi * 8);

    bf16x8 b[4];
    #pragma unroll
    for (int ni = 0; ni < 4; ++ni) {
      const int col = w * 64 + ni * 16 + lo;
      #pragma unroll
      for (int e = 0; e < 8; ++e)
        b[ni][e] = f2bf(lw[cur][hi * 8 + e][col]);
    }

    #pragma unroll
    for (int mi = 0; mi < 8; ++mi)
      #pragma unroll
      for (int ni = 0; ni < 4; ++ni)
        acc[mi][ni] = __builtin_amdgcn_mfma_f32_16x16x32_bf16(a[mi], b[ni], acc[mi][ni], 0, 0, 0);

    __syncthreads();
    cur ^= 1;
  }

  float* oj = out + (size_t)j * TOK * DM;
  #pragma unroll
  for (int ni = 0; ni < 4; ++ni) {
    const int d = t * TD + w * 64 + ni * 16 + lo;
    #pragma unroll
    for (int mi = 0; mi < 8; ++mi)
      #pragma unroll
      for (int rr = 0; rr < 4; ++rr)
        atomicAdd(oj + (size_t)(mi * 16 + hi * 4 + rr) * DM + d, acc[mi][ni][rr]);
  }
}

extern "C" void kernel_launch(void* const* d_in, const int* in_sizes, int n_in,
                              void* d_out, int out_size, void* d_ws, size_t ws_size,
                              hipStream_t stream) {
  const float* x     = (const float*)d_in[0];
  const float* W_enc = (const float*)d_in[1];
  const float* b_enc = (const float*)d_in[2];
  const float* b_dec = (const float*)d_in[3];
  const float* W_dec = (const float*)d_in[4];
  float* out = (float*)d_out;
  ushort* acts = (ushort*)d_ws;                      // 6*128*6144 bf16 = 9.44 MB
  ushort* xb   = acts + (size_t)NL * TOK * DT;       // 6*128*768 bf16 = 1.18 MB

  initcvt_k<<<dim3((NL * TOK * DM + 255) / 256), dim3(256), 0, stream>>>(b_dec, x, out, xb);
  encode_k<<<dim3(NL * 96), dim3(256), 0, stream>>>(xb, W_enc, b_enc, acts);
  decode_k<<<dim3(21 * NFC * NTD), dim3(256), 0, stream>>>(acts, W_dec, out);
}